// Round 13
// baseline (256.479 us; speedup 1.0000x reference)
//
#include <hip/hip_runtime.h>
#include <hip/hip_bf16.h>
#include <hip/hip_fp16.h>
#include <math.h>

typedef _Float16 f16x8 __attribute__((ext_vector_type(8)));
typedef __fp16  h16x2 __attribute__((ext_vector_type(2)));
typedef float f32x4 __attribute__((ext_vector_type(4)));

#define S_LEN 1024
#define DH 64
#define KVB 64
#define NIT 16
#define PROW 68   // P row pad: 4*68*2=544B row-group stride -> disjoint bank octets
#define THR 11.0f // defer-max threshold (log2 domain): P <= 2^11, fp16-safe

__device__ __forceinline__ unsigned rotl(unsigned x, unsigned r) {
  return __builtin_amdgcn_alignbit(x, x, 32u - r);  // single v_alignbit_b32
}

// JAX threefry2x32, key=(0,42), counts=(0,e) [threefry_partitionable].
// draw = x0 ^ x1; keep = top bit == 0 (uniform < 0.5).
__device__ __forceinline__ bool keep_bit(unsigned e) {
  const unsigned ks1 = 42u;
  const unsigned ks2 = 0x1BD11BF0u;  // 0 ^ 42 ^ 0x1BD11BDA
  unsigned x0 = 0u;
  unsigned x1 = e + ks1;
#define TFR(Ra,Rb,Rc,Rd) \
  x0 += x1; x1 = rotl(x1, Ra); x1 ^= x0; \
  x0 += x1; x1 = rotl(x1, Rb); x1 ^= x0; \
  x0 += x1; x1 = rotl(x1, Rc); x1 ^= x0; \
  x0 += x1; x1 = rotl(x1, Rd); x1 ^= x0;
  TFR(13u,15u,26u, 6u)  x0 += ks1; x1 += ks2 + 1u;
  TFR(17u,29u,16u,24u)  x0 += ks2; x1 += 2u;
  TFR(13u,15u,26u, 6u)  /* +0 */   x1 += ks1 + 3u;
  TFR(17u,29u,16u,24u)  x0 += ks1; x1 += ks2 + 4u;
  TFR(13u,15u,26u, 6u)  x0 += ks2; x1 += 5u;
#undef TFR
  return ((x0 ^ x1) >> 31) == 0u;
}

__device__ __forceinline__ f16x8 pk8(f32x4 a, f32x4 b) {
  h16x2 p0 = __builtin_amdgcn_cvt_pkrtz(a[0], a[1]);
  h16x2 p1 = __builtin_amdgcn_cvt_pkrtz(a[2], a[3]);
  h16x2 p2 = __builtin_amdgcn_cvt_pkrtz(b[0], b[1]);
  h16x2 p3 = __builtin_amdgcn_cvt_pkrtz(b[2], b[3]);
  f16x8 r;
  r[0]=(_Float16)p0[0]; r[1]=(_Float16)p0[1]; r[2]=(_Float16)p1[0]; r[3]=(_Float16)p1[1];
  r[4]=(_Float16)p2[0]; r[5]=(_Float16)p2[1]; r[6]=(_Float16)p3[0]; r[7]=(_Float16)p3[1];
  return r;
}

__global__ __launch_bounds__(256)
void attn_dropout_kernel(const float* __restrict__ Q, const float* __restrict__ K,
                         const float* __restrict__ V, float* __restrict__ out) {
  // BARRIER-FREE: 4 independent waves per block, 16 q-rows each.
  // K and V fragments loaded per-wave directly from global (L2-resident,
  // reused 64x); no shared LDS staging, no __syncthreads in the loop.
  // Only LDS use: wave-private P re-layout buffer (conflict-free pad 68).
  __shared__ _Float16 Pl[4][16][PROW];   // 8704 B

  const unsigned bh   = blockIdx.x >> 4;
  const unsigned q0   = (blockIdx.x & 15u) * 64u;
  const unsigned tid  = threadIdx.x;
  const unsigned w    = tid >> 6;
  const unsigned lane = tid & 63u;
  const unsigned g    = lane >> 4;     // 0..3
  const unsigned ln   = lane & 15u;    // 0..15
  const unsigned qw   = q0 + w * 16u;

  // ---- Q fragments, pre-scaled by 2*log2(e) ----
  f16x8 Qa0, Qa1;
  {
    const float* Qp = Q + (size_t)(bh * S_LEN + qw + ln) * DH + g * 8;
    const float s = 2.885390082f;  // 2 * log2(e): dropout 1/(1-p) + exp2 fold
    f32x4 a = *(const f32x4*)(Qp)      * s;
    f32x4 b = *(const f32x4*)(Qp + 4)  * s;
    f32x4 c = *(const f32x4*)(Qp + 32) * s;
    f32x4 d = *(const f32x4*)(Qp + 36) * s;
    Qa0 = pk8(a, b);
    Qa1 = pk8(c, d);
  }

  float mrun[4], lpart[4];
  f32x4 accO[4];
#pragma unroll
  for (int r = 0; r < 4; ++r) { mrun[r] = -1e30f; lpart[r] = 0.0f; }
#pragma unroll
  for (int n = 0; n < 4; ++n) accO[n] = (f32x4){0.f, 0.f, 0.f, 0.f};

  // K fragment base: row = t*64 + nt*16 + ln, cols g*8.. (vector 16B loads)
  const float* Kb = K + ((size_t)bh * S_LEN + ln) * DH + g * 8;
  // V fragment base: row = t*64 + g*8 + j, col = nd*16 + ln (scalar loads)
  const float* Vb = V + ((size_t)bh * S_LEN + g * 8) * DH + ln;

  for (int t = 0; t < NIT; ++t) {
    // ---- K frags direct from global + QK^T (immediate consume) ----
    f32x4 sc[4];
    {
      const float* Kt = Kb + (size_t)t * KVB * DH;
#pragma unroll
      for (int nt = 0; nt < 4; ++nt) {
        const float* Kp = Kt + nt * 16 * DH;
        f32x4 a = *(const f32x4*)(Kp);
        f32x4 b = *(const f32x4*)(Kp + 4);
        f32x4 c = *(const f32x4*)(Kp + 32);
        f32x4 d = *(const f32x4*)(Kp + 36);
        f16x8 kb0 = pk8(a, b);
        f16x8 kb1 = pk8(c, d);
        f32x4 acc = (f32x4){0.f, 0.f, 0.f, 0.f};
        acc = __builtin_amdgcn_mfma_f32_16x16x32_f16(Qa0, kb0, acc, 0, 0, 0);
        acc = __builtin_amdgcn_mfma_f32_16x16x32_f16(Qa1, kb1, acc, 0, 0, 0);
        sc[nt] = acc;
      }
    }

    // ---- dropout (threefry) + per-lane partial row max ----
    float sm[4][4];
    float pmx[4];
#pragma unroll
    for (int r = 0; r < 4; ++r) pmx[r] = -1e30f;
#pragma unroll
    for (int nt = 0; nt < 4; ++nt) {
#pragma unroll
      for (int r = 0; r < 4; ++r) {
        unsigned q  = qw + g * 4 + r;
        unsigned kg = (unsigned)t * KVB + nt * 16 + ln;
        unsigned e  = (bh << 20) + (q << 10) + kg;
        float v = keep_bit(e) ? sc[nt][r] : 0.0f;
        sm[nt][r] = v;
        pmx[r] = fmaxf(pmx[r], v);
      }
    }

    // ---- T13: ballot-gated max update + rescale (rare path) ----
    bool need = (pmx[0] > mrun[0] + THR) | (pmx[1] > mrun[1] + THR) |
                (pmx[2] > mrun[2] + THR) | (pmx[3] > mrun[3] + THR);
    if (__any(need)) {
#pragma unroll
      for (int r = 0; r < 4; ++r) {
        float mx = pmx[r];
#pragma unroll
        for (int off = 1; off < 16; off <<= 1) mx = fmaxf(mx, __shfl_xor(mx, off));
        float mn  = fmaxf(mrun[r], mx);
        float scl = exp2f(mrun[r] - mn);
        mrun[r] = mn;
        lpart[r] *= scl;
#pragma unroll
        for (int n = 0; n < 4; ++n) accO[n][r] *= scl;
      }
    }

    // ---- issue V fragment gathers (land during exp2/P phase below) ----
    f32x4 va[4], vbx[4], vc[4], vd[4];
    {
      const float* Vt = Vb + (size_t)t * KVB * DH;
#pragma unroll
      for (int nd = 0; nd < 4; ++nd) {
#pragma unroll
        for (int j = 0; j < 4; ++j) {
          va[nd][j]  = Vt[(j)      * DH + nd * 16];
          vbx[nd][j] = Vt[(4 + j)  * DH + nd * 16];
          vc[nd][j]  = Vt[(32 + j) * DH + nd * 16];
          vd[nd][j]  = Vt[(36 + j) * DH + nd * 16];
        }
      }
    }

    // ---- P = 2^(S - m); per-lane partial sum; P -> wave-private LDS ----
#pragma unroll
    for (int nt = 0; nt < 4; ++nt) {
#pragma unroll
      for (int r = 0; r < 4; ++r) {
        float p = exp2f(sm[nt][r] - mrun[r]);
        lpart[r] += p;
        Pl[w][g * 4 + r][nt * 16 + ln] = (_Float16)p;
      }
    }

    // ---- O += P V (convert V frags, then MFMA) ----
    f16x8 Pa0 = *(const f16x8*)&Pl[w][ln][g * 8];
    f16x8 Pa1 = *(const f16x8*)&Pl[w][ln][32 + g * 8];
#pragma unroll
    for (int nd = 0; nd < 4; ++nd) {
      f16x8 v0 = pk8(va[nd], vbx[nd]);   // k = g*8 + 0..7
      f16x8 v1 = pk8(vc[nd], vd[nd]);    // k = 32 + g*8 + 0..7
      accO[nd] = __builtin_amdgcn_mfma_f32_16x16x32_f16(Pa0, v0, accO[nd], 0, 0, 0);
      accO[nd] = __builtin_amdgcn_mfma_f32_16x16x32_f16(Pa1, v1, accO[nd], 0, 0, 0);
    }
  }

  // ---- epilogue: reduce l across the 16 k-lanes once, then O / l ----
  float lf[4];
#pragma unroll
  for (int r = 0; r < 4; ++r) {
    float l = lpart[r];
#pragma unroll
    for (int off = 1; off < 16; off <<= 1) l += __shfl_xor(l, off);
    lf[r] = l;
  }
#pragma unroll
  for (int nd = 0; nd < 4; ++nd) {
#pragma unroll
    for (int r = 0; r < 4; ++r) {
      unsigned q = qw + g * 4 + r;
      out[(size_t)(bh * S_LEN + q) * DH + nd * 16 + ln] = accO[nd][r] / lf[r];
    }
  }
}

extern "C" void kernel_launch(void* const* d_in, const int* in_sizes, int n_in,
                              void* d_out, int out_size, void* d_ws, size_t ws_size,
                              hipStream_t stream) {
  const float* Q = (const float*)d_in[0];
  const float* K = (const float*)d_in[1];
  const float* V = (const float*)d_in[2];
  float* out = (float*)d_out;
  dim3 grid(64 * 16);   // (b*16+h) * 16 q-tiles
  dim3 block(256);
  hipLaunchKernelGGL(attn_dropout_kernel, grid, block, 0, stream, Q, K, V, out);
}

// Round 14
// 254.390 us; speedup vs baseline: 1.0082x; 1.0082x over previous
//
#include <hip/hip_runtime.h>
#include <hip/hip_bf16.h>
#include <hip/hip_fp16.h>
#include <math.h>

typedef _Float16 f16x8 __attribute__((ext_vector_type(8)));
typedef __fp16  h16x2 __attribute__((ext_vector_type(2)));
typedef float f32x4 __attribute__((ext_vector_type(4)));

#define S_LEN 1024
#define DH 64
#define KVB 64
#define NIT 16
#define PROW 36   // P row pad (32 + 4)
#define THR 11.0f // defer-max threshold (log2 domain): P <= 2^11, fp16-safe

__device__ __forceinline__ unsigned rotl(unsigned x, unsigned r) {
  return __builtin_amdgcn_alignbit(x, x, 32u - r);  // single v_alignbit_b32
}

// JAX threefry2x32, key=(0,42), counts=(0,e) [threefry_partitionable].
// draw = x0 ^ x1; keep = top bit == 0 (uniform < 0.5).
__device__ __forceinline__ bool keep_bit(unsigned e) {
  const unsigned ks1 = 42u;
  const unsigned ks2 = 0x1BD11BF0u;  // 0 ^ 42 ^ 0x1BD11BDA
  unsigned x0 = 0u;
  unsigned x1 = e + ks1;
#define TFR(Ra,Rb,Rc,Rd) \
  x0 += x1; x1 = rotl(x1, Ra); x1 ^= x0; \
  x0 += x1; x1 = rotl(x1, Rb); x1 ^= x0; \
  x0 += x1; x1 = rotl(x1, Rc); x1 ^= x0; \
  x0 += x1; x1 = rotl(x1, Rd); x1 ^= x0;
  TFR(13u,15u,26u, 6u)  x0 += ks1; x1 += ks2 + 1u;
  TFR(17u,29u,16u,24u)  x0 += ks2; x1 += 2u;
  TFR(13u,15u,26u, 6u)  /* +0 */   x1 += ks1 + 3u;
  TFR(17u,29u,16u,24u)  x0 += ks1; x1 += ks2 + 4u;
  TFR(13u,15u,26u, 6u)  x0 += ks2; x1 += 5u;
#undef TFR
  return ((x0 ^ x1) >> 31) == 0u;
}

__device__ __forceinline__ f16x8 pk8(f32x4 a, f32x4 b) {
  h16x2 p0 = __builtin_amdgcn_cvt_pkrtz(a[0], a[1]);
  h16x2 p1 = __builtin_amdgcn_cvt_pkrtz(a[2], a[3]);
  h16x2 p2 = __builtin_amdgcn_cvt_pkrtz(b[0], b[1]);
  h16x2 p3 = __builtin_amdgcn_cvt_pkrtz(b[2], b[3]);
  f16x8 r;
  r[0]=(_Float16)p0[0]; r[1]=(_Float16)p0[1]; r[2]=(_Float16)p1[0]; r[3]=(_Float16)p1[1];
  r[4]=(_Float16)p2[0]; r[5]=(_Float16)p2[1]; r[6]=(_Float16)p3[0]; r[7]=(_Float16)p3[1];
  return r;
}

__global__ __launch_bounds__(512)
void attn_dropout_kernel(const float* __restrict__ Q, const float* __restrict__ K,
                         const float* __restrict__ V, float* __restrict__ out) {
  // TLP probe: 8 waves/block (512 thr), barrier-free loop, k-split 32/32
  // across wave pairs (w, w+4). K/V frags direct from global (L2-resident).
  // LDS: wave-private P buffer (9 KB) + merge overlay. 1024 blocks x 8 waves
  // -> up to 32 waves/CU (vs 16 before).
  __shared__ __align__(16) char smem[64*68*4 + 64*2*4];   // 17920 B
  _Float16* Pl = (_Float16*)smem;          // [8][16][PROW] loop phase
  float* Om = (float*)smem;                // [64][68]      merge phase (overlay)
  float* Ml = (float*)(smem + 64*68*4);    // [64][2]

  const unsigned bh   = blockIdx.x >> 4;
  const unsigned q0   = (blockIdx.x & 15u) * 64u;
  const unsigned tid  = threadIdx.x;
  const unsigned w    = tid >> 6;
  const unsigned lane = tid & 63u;
  const unsigned g    = lane >> 4;       // 0..3
  const unsigned ln   = lane & 15u;      // 0..15
  const unsigned p    = w & 3u;          // q-pair index
  const unsigned koff = (w >> 2) * 32u;  // this wave's k-half
  const unsigned qw   = q0 + p * 16u;

  // ---- Q fragments, pre-scaled by 2*log2(e) ----
  f16x8 Qa0, Qa1;
  {
    const float* Qp = Q + (size_t)(bh * S_LEN + qw + ln) * DH + g * 8;
    const float s = 2.885390082f;  // 2 * log2(e): dropout 1/(1-p) + exp2 fold
    f32x4 a = *(const f32x4*)(Qp)      * s;
    f32x4 b = *(const f32x4*)(Qp + 4)  * s;
    f32x4 c = *(const f32x4*)(Qp + 32) * s;
    f32x4 d = *(const f32x4*)(Qp + 36) * s;
    Qa0 = pk8(a, b);
    Qa1 = pk8(c, d);
  }

  float mrun[4], lpart[4];
  f32x4 accO[4];
#pragma unroll
  for (int r = 0; r < 4; ++r) { mrun[r] = -1e30f; lpart[r] = 0.0f; }
#pragma unroll
  for (int n = 0; n < 4; ++n) accO[n] = (f32x4){0.f, 0.f, 0.f, 0.f};

  // K frag base: row = t*64 + koff + nt*16 + ln, cols g*8.. (16B vec loads)
  const float* Kb = K + ((size_t)bh * S_LEN + koff + ln) * DH + g * 8;
  // V frag base: row = t*64 + koff + g*8 + j, col = nd*16 + ln (scalar)
  const float* Vb = V + ((size_t)bh * S_LEN + koff + g * 8) * DH + ln;

  for (int t = 0; t < NIT; ++t) {
    // ---- K frags + QK^T : 16 q-rows x 32 k-cols ----
    f32x4 sc[2];
    {
      const float* Kt = Kb + (size_t)t * KVB * DH;
#pragma unroll
      for (int nt = 0; nt < 2; ++nt) {
        const float* Kp = Kt + nt * 16 * DH;
        f32x4 a = *(const f32x4*)(Kp);
        f32x4 b = *(const f32x4*)(Kp + 4);
        f32x4 c = *(const f32x4*)(Kp + 32);
        f32x4 d = *(const f32x4*)(Kp + 36);
        f16x8 kb0 = pk8(a, b);
        f16x8 kb1 = pk8(c, d);
        f32x4 acc = (f32x4){0.f, 0.f, 0.f, 0.f};
        acc = __builtin_amdgcn_mfma_f32_16x16x32_f16(Qa0, kb0, acc, 0, 0, 0);
        acc = __builtin_amdgcn_mfma_f32_16x16x32_f16(Qa1, kb1, acc, 0, 0, 0);
        sc[nt] = acc;
      }
    }

    // ---- dropout (threefry), in-place mask; per-lane partial max ----
#pragma unroll
    for (int nt = 0; nt < 2; ++nt) {
#pragma unroll
      for (int r = 0; r < 4; ++r) {
        unsigned q  = qw + g * 4 + r;
        unsigned kg = (unsigned)t * KVB + koff + nt * 16 + ln;
        unsigned e  = (bh << 20) + (q << 10) + kg;
        sc[nt][r] = keep_bit(e) ? sc[nt][r] : 0.0f;
      }
    }
    float pmx[4];
#pragma unroll
    for (int r = 0; r < 4; ++r) pmx[r] = fmaxf(sc[0][r], sc[1][r]);

    // ---- T13: ballot-gated max update + rescale (rare path) ----
    bool need = (pmx[0] > mrun[0] + THR) | (pmx[1] > mrun[1] + THR) |
                (pmx[2] > mrun[2] + THR) | (pmx[3] > mrun[3] + THR);
    if (__any(need)) {
#pragma unroll
      for (int r = 0; r < 4; ++r) {
        float mx = pmx[r];
#pragma unroll
        for (int off = 1; off < 16; off <<= 1) mx = fmaxf(mx, __shfl_xor(mx, off));
        float mn  = fmaxf(mrun[r], mx);
        float scl = exp2f(mrun[r] - mn);
        mrun[r] = mn;
        lpart[r] *= scl;
#pragma unroll
        for (int n = 0; n < 4; ++n) accO[n][r] *= scl;
      }
    }

    // ---- V fragment gathers (32 scalar loads; land during exp2 phase) ----
    f32x4 va[4], vbx[4];
    {
      const float* Vt = Vb + (size_t)t * KVB * DH;
#pragma unroll
      for (int nd = 0; nd < 4; ++nd) {
#pragma unroll
        for (int j = 0; j < 4; ++j) {
          va[nd][j]  = Vt[(j)     * DH + nd * 16];
          vbx[nd][j] = Vt[(4 + j) * DH + nd * 16];
        }
      }
    }

    // ---- P = 2^(S - m); per-lane partial sum; P -> wave-private LDS ----
#pragma unroll
    for (int nt = 0; nt < 2; ++nt) {
#pragma unroll
      for (int r = 0; r < 4; ++r) {
        float pv = exp2f(sc[nt][r] - mrun[r]);
        lpart[r] += pv;
        Pl[(w * 16 + g * 4 + r) * PROW + nt * 16 + ln] = (_Float16)pv;
      }
    }

    // ---- O += P V (K-dim = 32 = one MFMA per nd) ----
    f16x8 Pa = *(const f16x8*)&Pl[(w * 16 + ln) * PROW + g * 8];
#pragma unroll
    for (int nd = 0; nd < 4; ++nd) {
      f16x8 v0 = pk8(va[nd], vbx[nd]);
      accO[nd] = __builtin_amdgcn_mfma_f32_16x16x32_f16(Pa, v0, accO[nd], 0, 0, 0);
    }
  }

  // ---- reduce lpart across 16 k-lanes (once) ----
#pragma unroll
  for (int r = 0; r < 4; ++r) {
    float l = lpart[r];
#pragma unroll
    for (int off = 1; off < 16; off <<= 1) l += __shfl_xor(l, off);
    lpart[r] = l;
  }

  // ---- merge wave pairs (w, w+4): 2 barriers total ----
  __syncthreads();   // all waves done with Pl before Om overlay
  if (w >= 4) {
#pragma unroll
    for (int nd = 0; nd < 4; ++nd)
#pragma unroll
      for (int r = 0; r < 4; ++r)
        Om[(p * 16 + g * 4 + r) * 68 + nd * 16 + ln] = accO[nd][r];
    if (ln == 0) {
#pragma unroll
      for (int r = 0; r < 4; ++r) {
        Ml[(p * 16 + g * 4 + r) * 2 + 0] = mrun[r];
        Ml[(p * 16 + g * 4 + r) * 2 + 1] = lpart[r];
      }
    }
  }
  __syncthreads();
  if (w < 4) {
    float e1[4], e2[4], lf[4];
#pragma unroll
    for (int r = 0; r < 4; ++r) {
      const unsigned row = p * 16 + g * 4 + r;
      float m2 = Ml[row * 2 + 0];
      float l2 = Ml[row * 2 + 1];
      float m  = fmaxf(mrun[r], m2);
      e1[r] = exp2f(mrun[r] - m);
      e2[r] = exp2f(m2 - m);
      lf[r] = lpart[r] * e1[r] + l2 * e2[r];
    }
#pragma unroll
    for (int nd = 0; nd < 4; ++nd)
#pragma unroll
      for (int r = 0; r < 4; ++r) {
        const unsigned row = p * 16 + g * 4 + r;
        float o = accO[nd][r] * e1[r] + Om[row * 68 + nd * 16 + ln] * e2[r];
        out[(size_t)(bh * S_LEN + q0 + row) * DH + nd * 16 + ln] = o / lf[r];
      }
  }
}

extern "C" void kernel_launch(void* const* d_in, const int* in_sizes, int n_in,
                              void* d_out, int out_size, void* d_ws, size_t ws_size,
                              hipStream_t stream) {
  const float* Q = (const float*)d_in[0];
  const float* K = (const float*)d_in[1];
  const float* V = (const float*)d_in[2];
  float* out = (float*)d_out;
  dim3 grid(64 * 16);   // (b*16+h) * 16 q-tiles
  dim3 block(512);
  hipLaunchKernelGGL(attn_dropout_kernel, grid, block, 0, stream, Q, K, V, out);
}